// Round 3
// baseline (57.312 us; speedup 1.0000x reference)
//
#include <hip/hip_runtime.h>

// RESCAL scoring: out[b] = e_h^T W_r e_t
// Round 3:
//   prep_k (1 block, 1024 thr): LDS histogram over relations -> scan ->
//     per-relation chunk descriptors (<=16 elems, one relation each) ->
//     scatter perm. One launch replaces 4.
//   rescal_main: 1 block = 1 descriptor (single relation). 4 waves split d
//     (32 rows each, W slice in 64 VGPRs, loaded once, unconditionally).
//     e_h broadcast via v_readlane (no LDS RAW chain). Elements fully
//     independent -> deep ILP. count==16 fast path fully unrolled.

#define RANK 128
#define CHUNK 16
#define MAXREL 1024

// ---------------- prep: hist + scan + descriptors + scatter, one block ----

__global__ __launch_bounds__(1024) void prep_k(
    const int* __restrict__ rels, int batch, int nrel,
    int4* __restrict__ desc, int* __restrict__ perm, int maxb)
{
  __shared__ int hist[MAXREL];
  __shared__ int tmp[MAXREL];
  __shared__ int startE[MAXREL];   // exclusive element offset per relation
  __shared__ int cursor[MAXREL];

  const int t = threadIdx.x;

  hist[t] = 0;
  __syncthreads();
  for (int i = t; i < batch; i += 1024) atomicAdd(&hist[rels[i]], 1);
  __syncthreads();

  const int cnt = (t < nrel) ? hist[t] : 0;

  // scan 1: element offsets
  tmp[t] = cnt;
  __syncthreads();
  for (int off = 1; off < 1024; off <<= 1) {
    int v = (t >= off) ? tmp[t - off] : 0;
    __syncthreads();
    tmp[t] += v;
    __syncthreads();
  }
  const int sE = tmp[t] - cnt;
  startE[t] = sE;
  cursor[t] = sE;

  // scan 2: block (descriptor) offsets
  const int nb = (cnt + CHUNK - 1) >> 4;
  __syncthreads();
  tmp[t] = nb;
  __syncthreads();
  for (int off = 1; off < 1024; off <<= 1) {
    int v = (t >= off) ? tmp[t - off] : 0;
    __syncthreads();
    tmp[t] += v;
    __syncthreads();
  }
  const int sB = tmp[t] - nb;
  const int totB = tmp[1023];

  for (int j = 0; j < nb; ++j) {
    int rem = cnt - CHUNK * j;
    desc[sB + j] = make_int4(t, sE + CHUNK * j, rem < CHUNK ? rem : CHUNK, 0);
  }
  for (int i = totB + t; i < maxb; i += 1024)
    desc[i] = make_int4(0, 0, 0, 0);

  __syncthreads();
  // scatter (stable enough: any order within a relation is fine)
  for (int i = t; i < batch; i += 1024) {
    int r = rels[i];
    int pos = atomicAdd(&cursor[r], 1);
    perm[pos] = i;
  }
}

// ---------------- main scoring kernel ----------------

__global__ __launch_bounds__(256) void rescal_main(
    const float* __restrict__ E, const float* __restrict__ W,
    const int* __restrict__ heads, const int* __restrict__ tails,
    const int* __restrict__ perm, const int4* __restrict__ desc,
    float* __restrict__ out)
{
  const int4 d4   = desc[blockIdx.x];
  const int r     = d4.x;
  const int start = d4.y;
  const int cnt   = d4.z;
  if (cnt == 0) return;                 // block-uniform

  const int wib  = threadIdx.x >> 6;    // wave owns d-rows [32*wib, 32*wib+32)
  const int lane = threadIdx.x & 63;    // lane owns cols {2*lane, 2*lane+1}

  __shared__ float part[4][CHUNK];

  // W_r slice for this wave: rows contiguous 16KB, 512B/row coalesced.
  float2 wreg[32];
  const float2* W2 = (const float2*)(W + (size_t)r * RANK * RANK);
  #pragma unroll
  for (int d = 0; d < 32; ++d)
    wreg[d] = W2[(wib * 32 + d) * 64 + lane];

  auto do_elem = [&](int e) {
    const int b = perm[start + e];      // block-uniform -> scalar loads
    const int h = heads[b];
    const int tt = tails[b];

    // lanes 0..31 hold e_h[wib*32 + lane]; 32..63 duplicate (same 128B line)
    const float ehv = E[(size_t)h * RANK + wib * 32 + (lane & 31)];
    const float2 et = ((const float2*)(E + (size_t)tt * RANK))[lane];

    float mx = 0.f, my = 0.f;
    #pragma unroll
    for (int d = 0; d < 32; ++d) {
      const float x = __int_as_float(
          __builtin_amdgcn_readlane(__float_as_int(ehv), d));  // SGPR broadcast
      mx = fmaf(x, wreg[d].x, mx);
      my = fmaf(x, wreg[d].y, my);
    }

    float sv = fmaf(mx, et.x, my * et.y);
    #pragma unroll
    for (int off = 32; off; off >>= 1)
      sv += __shfl_down(sv, off, 64);
    if (lane == 0) part[wib][e] = sv;
  };

  if (cnt == CHUNK) {
    #pragma unroll
    for (int e = 0; e < CHUNK; ++e) do_elem(e);
  } else {
    for (int e = 0; e < cnt; ++e) do_elem(e);
  }
  __syncthreads();

  if (threadIdx.x < cnt) {
    const float tot = part[0][threadIdx.x] + part[1][threadIdx.x]
                    + part[2][threadIdx.x] + part[3][threadIdx.x];
    out[perm[start + threadIdx.x]] = tot;
  }
}

// ---------------- launch ----------------

extern "C" void kernel_launch(void* const* d_in, const int* in_sizes, int n_in,
                              void* d_out, int out_size, void* d_ws, size_t ws_size,
                              hipStream_t stream)
{
  const float* E     = (const float*)d_in[0];
  const float* W     = (const float*)d_in[1];
  const int*   heads = (const int*)d_in[2];
  const int*   rels  = (const int*)d_in[3];
  const int*   tails = (const int*)d_in[4];
  float* out = (float*)d_out;

  const int batch = in_sizes[2];                  // 16384
  const int nrel  = in_sizes[1] / (RANK * RANK);  // 1000 (<= MAXREL)

  // Upper bound on descriptors: one partial chunk per relation + full chunks.
  const int maxb = nrel + (batch + CHUNK - 1) / CHUNK;   // <= 2024

  int4* desc = (int4*)d_ws;                        // [maxb]
  int*  perm = (int*)(desc + maxb);                // [batch]

  prep_k<<<1, 1024, 0, stream>>>(rels, batch, nrel, desc, perm, maxb);
  rescal_main<<<maxb, 256, 0, stream>>>(E, W, heads, tails, perm, desc, out);
}

// Round 4
// 53.259 us; speedup vs baseline: 1.0761x; 1.0761x over previous
//
#include <hip/hip_runtime.h>

// RESCAL scoring: out[b] = e_h^T W_r e_t
// Round 4: lgkm-free hot loop.
//   prep_k (1 block): LDS hist -> scan -> offs/cnts -> scatter perm.
//   rescal_main: 1 block = 1 relation. 4 waves split d (32 rows in 64 VGPRs).
//   Tile of 32 elements: indices gathered ONCE into VGPRs (vmcnt);
//   per-element h/t via v_readlane (VALU). Wave reduce via DPP
//   (row_shr 1/2/4/8 + row_bcast 15/31) -> no lgkmcnt in the loop.

#define RANK 128
#define MAXREL 1024

// ---------------- prep ----------------

__global__ __launch_bounds__(1024) void prep_k(
    const int* __restrict__ rels, int batch, int nrel,
    int* __restrict__ offs, int* __restrict__ cnts, int* __restrict__ perm)
{
  __shared__ int hist[MAXREL];
  __shared__ int tmp[MAXREL];
  __shared__ int cursor[MAXREL];
  const int t = threadIdx.x;

  hist[t] = 0;
  __syncthreads();

  const int nb4 = batch >> 2;
  const int4* r4 = (const int4*)rels;
  for (int i = t; i < nb4; i += 1024) {
    int4 v = r4[i];
    atomicAdd(&hist[v.x], 1); atomicAdd(&hist[v.y], 1);
    atomicAdd(&hist[v.z], 1); atomicAdd(&hist[v.w], 1);
  }
  for (int i = 4 * nb4 + t; i < batch; i += 1024) atomicAdd(&hist[rels[i]], 1);
  __syncthreads();

  const int cnt = hist[t];
  tmp[t] = cnt;
  __syncthreads();
  for (int off = 1; off < 1024; off <<= 1) {
    int v = (t >= off) ? tmp[t - off] : 0;
    __syncthreads();
    tmp[t] += v;
    __syncthreads();
  }
  const int sE = tmp[t] - cnt;     // exclusive prefix
  cursor[t] = sE;
  if (t < nrel) { offs[t] = sE; cnts[t] = cnt; }
  __syncthreads();

  for (int i = t; i < batch; i += 1024) {
    int r = rels[i];
    int pos = atomicAdd(&cursor[r], 1);
    perm[pos] = i;
  }
}

// ---------------- DPP 64-lane sum (result in lane 63), VALU-only ----------

__device__ __forceinline__ float dpp_sum64(float v) {
#define DPP_STEP(ctrl)                                                        \
  v += __int_as_float(__builtin_amdgcn_update_dpp(                            \
      0, __float_as_int(v), (ctrl), 0xf, 0xf, true))
  DPP_STEP(0x111);  // row_shr:1
  DPP_STEP(0x112);  // row_shr:2
  DPP_STEP(0x114);  // row_shr:4
  DPP_STEP(0x118);  // row_shr:8   -> lane15/31/47/63 hold 16-lane sums
  DPP_STEP(0x142);  // row_bcast:15 -> lane31 = 0..31, lane63 = 32..63
  DPP_STEP(0x143);  // row_bcast:31 -> lane63 = 0..63
#undef DPP_STEP
  return v;
}

// ---------------- main ----------------

__global__ __launch_bounds__(256) void rescal_main(
    const float* __restrict__ E, const float* __restrict__ W,
    const int* __restrict__ heads, const int* __restrict__ tails,
    const int* __restrict__ perm, const int* __restrict__ offs,
    const int* __restrict__ cnts, float* __restrict__ out)
{
  const int r   = blockIdx.x;
  const int cnt = cnts[r];
  if (cnt == 0) return;
  const int start = offs[r];

  const int wib  = threadIdx.x >> 6;   // wave owns d-rows [32*wib, 32*wib+32)
  const int lane = threadIdx.x & 63;   // lane owns cols {2*lane, 2*lane+1}
  const int l31  = lane & 31;

  __shared__ float part[4][32];

  // W_r slice for this wave, loaded once per relation.
  float2 wreg[32];
  const float2* W2 = (const float2*)(W + (size_t)r * RANK * RANK);
  #pragma unroll
  for (int d = 0; d < 32; ++d)
    wreg[d] = W2[(wib * 32 + d) * 64 + lane];

  for (int tb = 0; tb < cnt; tb += 32) {
    const int tc = min(32, cnt - tb);

    // Gather this tile's indices into VGPRs (lanes 0..tc-1; others clamp).
    const int li = (l31 < tc) ? l31 : 0;
    const int bv = perm[start + tb + li];
    const int hv = heads[bv];
    const int tv = tails[bv];

    for (int e0 = 0; e0 < tc; e0 += 4) {
      #pragma unroll
      for (int u = 0; u < 4; ++u) {
        const int e   = e0 + u;
        const int ecl = (e < tc) ? e : 0;
        const int h = __builtin_amdgcn_readlane(hv, ecl);   // VALU, no lgkm
        const int t = __builtin_amdgcn_readlane(tv, ecl);

        const float  eh = E[(size_t)(unsigned)h * RANK + wib * 32 + l31];
        const float2 et = ((const float2*)(E + (size_t)(unsigned)t * RANK))[lane];

        float mx = 0.f, my = 0.f;
        #pragma unroll
        for (int d = 0; d < 32; ++d) {
          const float x = __int_as_float(
              __builtin_amdgcn_readlane(__float_as_int(eh), d));
          mx = fmaf(x, wreg[d].x, mx);
          my = fmaf(x, wreg[d].y, my);
        }

        float sv = fmaf(mx, et.x, my * et.y);
        sv = dpp_sum64(sv);
        if (lane == 63 && e < tc) part[wib][e] = sv;
      }
    }
    __syncthreads();

    if (threadIdx.x < tc)   // thread tid is wave 0 lane tid -> has bv for elem tid
      out[bv] = part[0][threadIdx.x] + part[1][threadIdx.x]
              + part[2][threadIdx.x] + part[3][threadIdx.x];
    __syncthreads();        // part reused next tile
  }
}

// ---------------- launch ----------------

extern "C" void kernel_launch(void* const* d_in, const int* in_sizes, int n_in,
                              void* d_out, int out_size, void* d_ws, size_t ws_size,
                              hipStream_t stream)
{
  const float* E     = (const float*)d_in[0];
  const float* W     = (const float*)d_in[1];
  const int*   heads = (const int*)d_in[2];
  const int*   rels  = (const int*)d_in[3];
  const int*   tails = (const int*)d_in[4];
  float* out = (float*)d_out;

  const int batch = in_sizes[2];                  // 16384
  const int nrel  = in_sizes[1] / (RANK * RANK);  // 1000 (<= MAXREL)

  int* offs = (int*)d_ws;            // [MAXREL]
  int* cnts = offs + MAXREL;         // [MAXREL]
  int* perm = cnts + MAXREL;         // [batch]

  prep_k<<<1, 1024, 0, stream>>>(rels, batch, nrel, offs, cnts, perm);
  rescal_main<<<nrel, 256, 0, stream>>>(E, W, heads, tails, perm, offs, cnts, out);
}

// Round 5
// 44.011 us; speedup vs baseline: 1.3022x; 1.2101x over previous
//
#include <hip/hip_runtime.h>

// RESCAL scoring: out[b] = e_h^T W_r e_t
// Round 5: SINGLE kernel, zero prep. Block r scans rels[] itself (64KB from
// L2/L3, 1000-way broadcast), compacts matching batch indices into LDS via
// atomics, then runs round-4's compute loop: W_r slice in 64 VGPRs (4 waves
// x 32 d-rows), e_h broadcast via v_readlane, DPP wave reduce. No lgkm in
// the inner loop, no workspace, no launch chain.

#define RANK 128
#define LCAP 1024   // per-relation element capacity (batch/nrel avg 16.4)

__device__ __forceinline__ float dpp_sum64(float v) {
#define DPP_STEP(ctrl)                                                        \
  v += __int_as_float(__builtin_amdgcn_update_dpp(                            \
      0, __float_as_int(v), (ctrl), 0xf, 0xf, true))
  DPP_STEP(0x111);  // row_shr:1
  DPP_STEP(0x112);  // row_shr:2
  DPP_STEP(0x114);  // row_shr:4
  DPP_STEP(0x118);  // row_shr:8   -> lanes 15/31/47/63 hold 16-lane sums
  DPP_STEP(0x142);  // row_bcast:15 -> lane31 = sum 0..31, lane63 = 32..63
  DPP_STEP(0x143);  // row_bcast:31 -> lane63 = sum 0..63
#undef DPP_STEP
  return v;
}

__global__ __launch_bounds__(256) void rescal_one(
    const float* __restrict__ E, const float* __restrict__ W,
    const int* __restrict__ heads, const int* __restrict__ rels,
    const int* __restrict__ tails, float* __restrict__ out, int batch)
{
  const int r    = blockIdx.x;
  const int wib  = threadIdx.x >> 6;   // wave owns d-rows [32*wib, 32*wib+32)
  const int lane = threadIdx.x & 63;   // lane owns cols {2*lane, 2*lane+1}
  const int l31  = lane & 31;

  __shared__ int   list[LCAP];
  __shared__ int   lcnt;
  __shared__ float part[4][32];

  if (threadIdx.x == 0) lcnt = 0;
  __syncthreads();

  // ---- scan rels, compact matching indices (independent int4 loads) ----
  const int nb4 = batch >> 2;
  const int4* r4 = (const int4*)rels;
  for (int i = threadIdx.x; i < nb4; i += 256) {
    const int4 v = r4[i];
    if (v.x == r) { int p = atomicAdd(&lcnt, 1); if (p < LCAP) list[p] = 4*i;   }
    if (v.y == r) { int p = atomicAdd(&lcnt, 1); if (p < LCAP) list[p] = 4*i+1; }
    if (v.z == r) { int p = atomicAdd(&lcnt, 1); if (p < LCAP) list[p] = 4*i+2; }
    if (v.w == r) { int p = atomicAdd(&lcnt, 1); if (p < LCAP) list[p] = 4*i+3; }
  }
  for (int i = 4*nb4 + threadIdx.x; i < batch; i += 256)
    if (rels[i] == r) { int p = atomicAdd(&lcnt, 1); if (p < LCAP) list[p] = i; }

  // ---- W_r slice for this wave (overlaps with the scan's tail) ----
  float2 wreg[32];
  const float2* W2 = (const float2*)(W + (size_t)r * RANK * RANK);
  #pragma unroll
  for (int d = 0; d < 32; ++d)
    wreg[d] = W2[(wib * 32 + d) * 64 + lane];

  __syncthreads();
  const int cnt = min(lcnt, LCAP);

  // ---- compute: tiles of 32 elements ----
  for (int tb = 0; tb < cnt; tb += 32) {
    const int tc = min(32, cnt - tb);

    const int li = (l31 < tc) ? l31 : 0;
    const int bv = list[tb + li];        // LDS read, once per tile
    const int hv = heads[bv];
    const int tv = tails[bv];

    for (int e0 = 0; e0 < tc; e0 += 4) {
      #pragma unroll
      for (int u = 0; u < 4; ++u) {
        const int e   = e0 + u;
        const int ecl = (e < tc) ? e : 0;
        const int h = __builtin_amdgcn_readlane(hv, ecl);   // VALU, no lgkm
        const int t = __builtin_amdgcn_readlane(tv, ecl);

        const float  eh = E[(size_t)(unsigned)h * RANK + wib * 32 + l31];
        const float2 et = ((const float2*)(E + (size_t)(unsigned)t * RANK))[lane];

        float mx = 0.f, my = 0.f;
        #pragma unroll
        for (int d = 0; d < 32; ++d) {
          const float x = __int_as_float(
              __builtin_amdgcn_readlane(__float_as_int(eh), d));
          mx = fmaf(x, wreg[d].x, mx);
          my = fmaf(x, wreg[d].y, my);
        }

        float sv = fmaf(mx, et.x, my * et.y);
        sv = dpp_sum64(sv);
        if (lane == 63 && e < tc) part[wib][e] = sv;
      }
    }
    __syncthreads();

    if (threadIdx.x < tc)  // thread tid is wave-0 lane tid -> holds bv for elem tid
      out[bv] = part[0][threadIdx.x] + part[1][threadIdx.x]
              + part[2][threadIdx.x] + part[3][threadIdx.x];
    __syncthreads();       // part[] reused next tile
  }
}

extern "C" void kernel_launch(void* const* d_in, const int* in_sizes, int n_in,
                              void* d_out, int out_size, void* d_ws, size_t ws_size,
                              hipStream_t stream)
{
  const float* E     = (const float*)d_in[0];
  const float* W     = (const float*)d_in[1];
  const int*   heads = (const int*)d_in[2];
  const int*   rels  = (const int*)d_in[3];
  const int*   tails = (const int*)d_in[4];
  float* out = (float*)d_out;

  const int batch = in_sizes[2];                  // 16384
  const int nrel  = in_sizes[1] / (RANK * RANK);  // 1000

  rescal_one<<<nrel, 256, 0, stream>>>(E, W, heads, rels, tails, out, batch);
}

// Round 6
// 41.113 us; speedup vs baseline: 1.3940x; 1.0705x over previous
//
#include <hip/hip_runtime.h>

// RESCAL scoring: out[b] = e_h^T W_r e_t
// Round 6: R5 structure, 2x TLP, half-length chains.
//   Single kernel. Block r: 512 threads = 8 waves; scan rels -> LDS list;
//   wave owns 16 d-rows of W_r in 32 VGPRs; e_h broadcast via v_readlane
//   (16-deep chain, was 32); DPP wave reduce; part[8][32] combine.

#define RANK 128
#define LCAP 1024

__device__ __forceinline__ float dpp_sum64(float v) {
#define DPP_STEP(ctrl)                                                        \
  v += __int_as_float(__builtin_amdgcn_update_dpp(                            \
      0, __float_as_int(v), (ctrl), 0xf, 0xf, true))
  DPP_STEP(0x111);  // row_shr:1
  DPP_STEP(0x112);  // row_shr:2
  DPP_STEP(0x114);  // row_shr:4
  DPP_STEP(0x118);  // row_shr:8   -> lanes 15/31/47/63 hold 16-lane sums
  DPP_STEP(0x142);  // row_bcast:15 -> lane31 = sum 0..31, lane63 = 32..63
  DPP_STEP(0x143);  // row_bcast:31 -> lane63 = sum 0..63
#undef DPP_STEP
  return v;
}

__global__ __launch_bounds__(512) void rescal_one(
    const float* __restrict__ E, const float* __restrict__ W,
    const int* __restrict__ heads, const int* __restrict__ rels,
    const int* __restrict__ tails, float* __restrict__ out, int batch)
{
  const int r    = blockIdx.x;
  const int wib  = threadIdx.x >> 6;   // wave 0..7 owns d-rows [16*wib, 16*wib+16)
  const int lane = threadIdx.x & 63;   // lane owns cols {2*lane, 2*lane+1}
  const int l31  = lane & 31;

  __shared__ int   list[LCAP];
  __shared__ int   lcnt;
  __shared__ float part[8][32];

  if (threadIdx.x == 0) lcnt = 0;
  __syncthreads();

  // ---- scan rels, compact matching indices ----
  const int nb4 = batch >> 2;
  const int4* r4 = (const int4*)rels;
  for (int i = threadIdx.x; i < nb4; i += 512) {
    const int4 v = r4[i];
    if (v.x == r) { int p = atomicAdd(&lcnt, 1); if (p < LCAP) list[p] = 4*i;   }
    if (v.y == r) { int p = atomicAdd(&lcnt, 1); if (p < LCAP) list[p] = 4*i+1; }
    if (v.z == r) { int p = atomicAdd(&lcnt, 1); if (p < LCAP) list[p] = 4*i+2; }
    if (v.w == r) { int p = atomicAdd(&lcnt, 1); if (p < LCAP) list[p] = 4*i+3; }
  }
  for (int i = 4*nb4 + threadIdx.x; i < batch; i += 512)
    if (rels[i] == r) { int p = atomicAdd(&lcnt, 1); if (p < LCAP) list[p] = i; }

  // ---- W_r slice: 16 rows x {2*lane, 2*lane+1} in 32 VGPRs ----
  float2 wreg[16];
  const float2* W2 = (const float2*)(W + (size_t)r * RANK * RANK);
  #pragma unroll
  for (int d = 0; d < 16; ++d)
    wreg[d] = W2[(wib * 16 + d) * 64 + lane];

  __syncthreads();
  const int cnt = min(lcnt, LCAP);

  // ---- compute: tiles of 32 elements ----
  for (int tb = 0; tb < cnt; tb += 32) {
    const int tc = min(32, cnt - tb);

    const int li = (l31 < tc) ? l31 : 0;
    const int bv = list[tb + li];        // LDS read, once per tile
    const int hv = heads[bv];
    const int tv = tails[bv];

    for (int e0 = 0; e0 < tc; e0 += 4) {
      #pragma unroll
      for (int u = 0; u < 4; ++u) {
        const int e   = e0 + u;
        const int ecl = (e < tc) ? e : 0;
        const int h = __builtin_amdgcn_readlane(hv, ecl);   // VALU, no lgkm
        const int t = __builtin_amdgcn_readlane(tv, ecl);

        // lanes 0..15 map to this wave's 16 d-values (one 64B line/wave)
        const float  eh = E[(size_t)(unsigned)h * RANK + wib * 16 + (lane & 15)];
        const float2 et = ((const float2*)(E + (size_t)(unsigned)t * RANK))[lane];

        float mx = 0.f, my = 0.f;
        #pragma unroll
        for (int d = 0; d < 16; ++d) {
          const float x = __int_as_float(
              __builtin_amdgcn_readlane(__float_as_int(eh), d));
          mx = fmaf(x, wreg[d].x, mx);
          my = fmaf(x, wreg[d].y, my);
        }

        float sv = fmaf(mx, et.x, my * et.y);
        sv = dpp_sum64(sv);
        if (lane == 63 && e < tc) part[wib][e] = sv;
      }
    }
    __syncthreads();

    if (threadIdx.x < tc) {  // wave-0 lanes 0..tc-1 hold bv for elem tid
      float tot = 0.f;
      #pragma unroll
      for (int w = 0; w < 8; ++w) tot += part[w][threadIdx.x];
      out[bv] = tot;
    }
    __syncthreads();         // part[]/list reuse next tile
  }
}

extern "C" void kernel_launch(void* const* d_in, const int* in_sizes, int n_in,
                              void* d_out, int out_size, void* d_ws, size_t ws_size,
                              hipStream_t stream)
{
  const float* E     = (const float*)d_in[0];
  const float* W     = (const float*)d_in[1];
  const int*   heads = (const int*)d_in[2];
  const int*   rels  = (const int*)d_in[3];
  const int*   tails = (const int*)d_in[4];
  float* out = (float*)d_out;

  const int batch = in_sizes[2];                  // 16384
  const int nrel  = in_sizes[1] / (RANK * RANK);  // 1000

  rescal_one<<<nrel, 512, 0, stream>>>(E, W, heads, rels, tails, out, batch);
}

// Round 7
// 40.022 us; speedup vs baseline: 1.4320x; 1.0273x over previous
//
#include <hip/hip_runtime.h>

// RESCAL scoring: out[b] = e_h^T W_r e_t
// Round 7: R6 + Et staged ONCE per tile in LDS (kills the 8x per-wave
// duplication ~58 MB of L3 traffic) + W_r register loads hoisted above the
// rels scan (latency overlap). Compute loop unchanged: e_h broadcast via
// v_readlane, 16-row fma per wave, DPP wave reduce.

#define RANK 128
#define LCAP 1024
#define TILE 32

__device__ __forceinline__ float dpp_sum64(float v) {
#define DPP_STEP(ctrl)                                                        \
  v += __int_as_float(__builtin_amdgcn_update_dpp(                            \
      0, __float_as_int(v), (ctrl), 0xf, 0xf, true))
  DPP_STEP(0x111);  // row_shr:1
  DPP_STEP(0x112);  // row_shr:2
  DPP_STEP(0x114);  // row_shr:4
  DPP_STEP(0x118);  // row_shr:8   -> lanes 15/31/47/63 hold 16-lane sums
  DPP_STEP(0x142);  // row_bcast:15 -> lane31 = sum 0..31, lane63 = 32..63
  DPP_STEP(0x143);  // row_bcast:31 -> lane63 = sum 0..63
#undef DPP_STEP
  return v;
}

__global__ __launch_bounds__(512) void rescal_one(
    const float* __restrict__ E, const float* __restrict__ W,
    const int* __restrict__ heads, const int* __restrict__ rels,
    const int* __restrict__ tails, float* __restrict__ out, int batch)
{
  const int r    = blockIdx.x;
  const int wib  = threadIdx.x >> 6;   // wave 0..7 owns d-rows [16*wib, 16*wib+16)
  const int lane = threadIdx.x & 63;   // lane owns cols {2*lane, 2*lane+1}
  const int l31  = lane & 31;

  __shared__ int   list[LCAP];
  __shared__ int   lcnt;
  __shared__ float part[8][TILE];
  __shared__ float ets[TILE][RANK];    // staged e_t tile, shared by all waves
  __shared__ int   tsl[TILE];

  if (threadIdx.x == 0) lcnt = 0;
  __syncthreads();

  // ---- W_r slice: issue FIRST so the ~500cy latency overlaps the scan ----
  float2 wreg[16];
  const float2* W2 = (const float2*)(W + (size_t)r * RANK * RANK);
  #pragma unroll
  for (int d = 0; d < 16; ++d)
    wreg[d] = W2[(wib * 16 + d) * 64 + lane];

  // ---- scan rels, compact matching indices into LDS list ----
  const int nb4 = batch >> 2;
  const int4* r4 = (const int4*)rels;
  for (int i = threadIdx.x; i < nb4; i += 512) {
    const int4 v = r4[i];
    if (v.x == r) { int p = atomicAdd(&lcnt, 1); if (p < LCAP) list[p] = 4*i;   }
    if (v.y == r) { int p = atomicAdd(&lcnt, 1); if (p < LCAP) list[p] = 4*i+1; }
    if (v.z == r) { int p = atomicAdd(&lcnt, 1); if (p < LCAP) list[p] = 4*i+2; }
    if (v.w == r) { int p = atomicAdd(&lcnt, 1); if (p < LCAP) list[p] = 4*i+3; }
  }
  for (int i = 4*nb4 + threadIdx.x; i < batch; i += 512)
    if (rels[i] == r) { int p = atomicAdd(&lcnt, 1); if (p < LCAP) list[p] = i; }

  __syncthreads();
  const int cnt = min(lcnt, LCAP);

  // ---- compute: tiles of 32 elements ----
  for (int tb = 0; tb < cnt; tb += TILE) {
    const int tc = min(TILE, cnt - tb);

    // Per-wave VGPR gather of this tile's indices (lanes 0..tc-1).
    const int li = (l31 < tc) ? l31 : 0;
    const int bv = list[tb + li];
    const int hv = heads[bv];
    const int tv = tails[bv];
    if (threadIdx.x < 32) tsl[threadIdx.x] = tv;   // wave 0 publishes tails
    __syncthreads();

    // Stage Et tile once (tc rows x 512B, coalesced float4), shared by waves.
    const int nf4 = tc * 32;                       // 32 float4 per row
    for (int idx = threadIdx.x; idx < nf4; idx += 512) {
      const int e = idx >> 5, w4 = idx & 31;
      const float4 v = ((const float4*)(E + (size_t)(unsigned)tsl[e] * RANK))[w4];
      ((float4*)ets[e])[w4] = v;
    }
    __syncthreads();

    for (int e0 = 0; e0 < tc; e0 += 4) {
      #pragma unroll
      for (int u = 0; u < 4; ++u) {
        const int e   = e0 + u;
        const int ecl = (e < tc) ? e : 0;
        const int h = __builtin_amdgcn_readlane(hv, ecl);   // VALU, no lgkm

        // e_h slice for this wave: 64B line, quad-broadcast across lanes.
        const float eh = E[(size_t)(unsigned)h * RANK + wib * 16 + (lane & 15)];
        // e_t from LDS: words 0..127 exactly once per wave -> conflict-free.
        const float2 et = ((const float2*)ets[ecl])[lane];

        float mx = 0.f, my = 0.f;
        #pragma unroll
        for (int d = 0; d < 16; ++d) {
          const float x = __int_as_float(
              __builtin_amdgcn_readlane(__float_as_int(eh), d));
          mx = fmaf(x, wreg[d].x, mx);
          my = fmaf(x, wreg[d].y, my);
        }

        float sv = fmaf(mx, et.x, my * et.y);
        sv = dpp_sum64(sv);
        if (lane == 63 && e < tc) part[wib][e] = sv;
      }
    }
    __syncthreads();

    if (threadIdx.x < tc) {  // wave-0 lanes 0..tc-1 hold bv for elem tid
      float tot = 0.f;
      #pragma unroll
      for (int w = 0; w < 8; ++w) tot += part[w][threadIdx.x];
      out[bv] = tot;
    }
    __syncthreads();         // part/ets/tsl reused next tile
  }
}

extern "C" void kernel_launch(void* const* d_in, const int* in_sizes, int n_in,
                              void* d_out, int out_size, void* d_ws, size_t ws_size,
                              hipStream_t stream)
{
  const float* E     = (const float*)d_in[0];
  const float* W     = (const float*)d_in[1];
  const int*   heads = (const int*)d_in[2];
  const int*   rels  = (const int*)d_in[3];
  const int*   tails = (const int*)d_in[4];
  float* out = (float*)d_out;

  const int batch = in_sizes[2];                  // 16384
  const int nrel  = in_sizes[1] / (RANK * RANK);  // 1000

  rescal_one<<<nrel, 512, 0, stream>>>(E, W, heads, rels, tails, out, batch);
}

// Round 8
// 38.624 us; speedup vs baseline: 1.4838x; 1.0362x over previous
//
#include <hip/hip_runtime.h>

// RESCAL scoring: out[b] = e_h^T W_r e_t
// Round 8: single-exposure tile latency.
//   Block r: scan rels -> LDS list (as R5-R7). Per 32-elem tile:
//   publish hsl/tsl -> barrier -> issue ALL memory up-front:
//   8 packed e_h loads (1 vmem covers 4 elems x 16 d via lane layout
//   (l>>4)=elem, (l&15)=d) + e_t tile staged to LDS (float4) -> barrier ->
//   pure-VALU compute (readlane broadcast, 16-row fma, DPP reduce).

#define RANK 128
#define LCAP 1024
#define TILE 32

__device__ __forceinline__ float dpp_sum64(float v) {
#define DPP_STEP(ctrl)                                                        \
  v += __int_as_float(__builtin_amdgcn_update_dpp(                            \
      0, __float_as_int(v), (ctrl), 0xf, 0xf, true))
  DPP_STEP(0x111);  // row_shr:1
  DPP_STEP(0x112);  // row_shr:2
  DPP_STEP(0x114);  // row_shr:4
  DPP_STEP(0x118);  // row_shr:8   -> lanes 15/31/47/63 hold 16-lane sums
  DPP_STEP(0x142);  // row_bcast:15 -> lane31 = sum 0..31, lane63 = 32..63
  DPP_STEP(0x143);  // row_bcast:31 -> lane63 = sum 0..63
#undef DPP_STEP
  return v;
}

__global__ __launch_bounds__(512) void rescal_one(
    const float* __restrict__ E, const float* __restrict__ W,
    const int* __restrict__ heads, const int* __restrict__ rels,
    const int* __restrict__ tails, float* __restrict__ out, int batch)
{
  const int r    = blockIdx.x;
  const int wib  = threadIdx.x >> 6;   // wave 0..7 owns d-rows [16*wib, 16*wib+16)
  const int lane = threadIdx.x & 63;   // lane owns cols {2*lane, 2*lane+1}
  const int l31  = lane & 31;

  __shared__ int   list[LCAP];
  __shared__ int   lcnt;
  __shared__ int   hsl[TILE], tsl[TILE];
  __shared__ float part[8][TILE];
  __shared__ float ets[TILE][RANK];

  if (threadIdx.x == 0) lcnt = 0;
  __syncthreads();

  // W_r slice first: ~500cy latency overlaps the scan below.
  float2 wreg[16];
  const float2* W2 = (const float2*)(W + (size_t)r * RANK * RANK);
  #pragma unroll
  for (int d = 0; d < 16; ++d)
    wreg[d] = W2[(wib * 16 + d) * 64 + lane];

  // ---- scan rels, compact matching indices ----
  const int nb4 = batch >> 2;
  const int4* r4 = (const int4*)rels;
  for (int i = threadIdx.x; i < nb4; i += 512) {
    const int4 v = r4[i];
    if (v.x == r) { int p = atomicAdd(&lcnt, 1); if (p < LCAP) list[p] = 4*i;   }
    if (v.y == r) { int p = atomicAdd(&lcnt, 1); if (p < LCAP) list[p] = 4*i+1; }
    if (v.z == r) { int p = atomicAdd(&lcnt, 1); if (p < LCAP) list[p] = 4*i+2; }
    if (v.w == r) { int p = atomicAdd(&lcnt, 1); if (p < LCAP) list[p] = 4*i+3; }
  }
  for (int i = 4*nb4 + threadIdx.x; i < batch; i += 512)
    if (rels[i] == r) { int p = atomicAdd(&lcnt, 1); if (p < LCAP) list[p] = i; }

  __syncthreads();
  const int cnt = min(lcnt, LCAP);

  for (int tb = 0; tb < cnt; tb += TILE) {
    const int tc = min(TILE, cnt - tb);

    int bv = 0;
    if (threadIdx.x < TILE) {            // wave-0 lanes publish indices
      bv = list[tb + min(l31, tc - 1)];
      hsl[l31] = heads[bv];
      tsl[l31] = tails[bv];
    }
    __syncthreads();

    // ---- ALL tile memory up-front, one latency exposure ----
    // packed e_h: 1 vmem instr covers 4 elems x 16 d-values
    float ehg[8];
    #pragma unroll
    for (int g = 0; g < 8; ++g) {
      const int hh = hsl[4 * g + (lane >> 4)];          // 16-lane broadcast
      ehg[g] = E[(size_t)(unsigned)hh * RANK + wib * 16 + (lane & 15)];
    }
    // e_t tile -> LDS (tc rows x 512B, coalesced float4)
    const int nf4 = tc * 32;
    for (int idx = threadIdx.x; idx < nf4; idx += 512) {
      const int e = idx >> 5, w4 = idx & 31;
      ((float4*)ets[e])[w4] =
          ((const float4*)(E + (size_t)(unsigned)tsl[e] * RANK))[w4];
    }
    __syncthreads();

    // ---- pure-VALU compute ----
    for (int g = 0; g < 8; ++g) {
      if (4 * g >= tc) break;            // block-uniform
      #pragma unroll
      for (int u = 0; u < 4; ++u) {
        const int e   = 4 * g + u;
        const int ecl = (e < tc) ? e : 0;
        const float2 et = ((const float2*)ets[ecl])[lane];

        float mx = 0.f, my = 0.f;
        #pragma unroll
        for (int d = 0; d < 16; ++d) {
          const float x = __int_as_float(__builtin_amdgcn_readlane(
              __float_as_int(ehg[g]), u * 16 + d));
          mx = fmaf(x, wreg[d].x, mx);
          my = fmaf(x, wreg[d].y, my);
        }

        float sv = fmaf(mx, et.x, my * et.y);
        sv = dpp_sum64(sv);
        if (lane == 63 && e < tc) part[wib][e] = sv;
      }
    }
    __syncthreads();

    if (threadIdx.x < tc) {              // wave-0 lane l holds bv for elem l
      float tot = 0.f;
      #pragma unroll
      for (int w = 0; w < 8; ++w) tot += part[w][threadIdx.x];
      out[bv] = tot;
    }
    __syncthreads();                     // LDS reused next tile
  }
}

extern "C" void kernel_launch(void* const* d_in, const int* in_sizes, int n_in,
                              void* d_out, int out_size, void* d_ws, size_t ws_size,
                              hipStream_t stream)
{
  const float* E     = (const float*)d_in[0];
  const float* W     = (const float*)d_in[1];
  const int*   heads = (const int*)d_in[2];
  const int*   rels  = (const int*)d_in[3];
  const int*   tails = (const int*)d_in[4];
  float* out = (float*)d_out;

  const int batch = in_sizes[2];                  // 16384
  const int nrel  = in_sizes[1] / (RANK * RANK);  // 1000

  rescal_one<<<nrel, 512, 0, stream>>>(E, W, heads, rels, tails, out, batch);
}

// Round 9
// 38.122 us; speedup vs baseline: 1.5034x; 1.0132x over previous
//
#include <hip/hip_runtime.h>

// RESCAL scoring: out[b] = e_h^T W_r e_t
// Round 9: R8 + clamp-free padded tiles + barrier elision.
//   Block r: scan rels -> LDS list; publish clamped hsl/tsl (32 lanes);
//   single-exposure tile memory (8 packed e_h vmem + e_t tile -> LDS);
//   pure-VALU compute: readlane broadcast, 16-row fma, DPP reduce.
//   Tiles padded to x4 elements (clamped indices) -> no per-elem selects.

#define RANK 128
#define LCAP 1024
#define TILE 32

__device__ __forceinline__ float dpp_sum64(float v) {
#define DPP_STEP(ctrl)                                                        \
  v += __int_as_float(__builtin_amdgcn_update_dpp(                            \
      0, __float_as_int(v), (ctrl), 0xf, 0xf, true))
  DPP_STEP(0x111);  // row_shr:1
  DPP_STEP(0x112);  // row_shr:2
  DPP_STEP(0x114);  // row_shr:4
  DPP_STEP(0x118);  // row_shr:8   -> lanes 15/31/47/63 hold 16-lane sums
  DPP_STEP(0x142);  // row_bcast:15 -> lane31 = sum 0..31, lane63 = 32..63
  DPP_STEP(0x143);  // row_bcast:31 -> lane63 = sum 0..63
#undef DPP_STEP
  return v;
}

__global__ __launch_bounds__(512) void rescal_one(
    const float* __restrict__ E, const float* __restrict__ W,
    const int* __restrict__ heads, const int* __restrict__ rels,
    const int* __restrict__ tails, float* __restrict__ out, int batch)
{
  const int r    = blockIdx.x;
  const int wib  = threadIdx.x >> 6;   // wave 0..7 owns d-rows [16*wib, 16*wib+16)
  const int lane = threadIdx.x & 63;   // lane owns cols {2*lane, 2*lane+1}
  const int l31  = lane & 31;

  __shared__ int   list[LCAP];
  __shared__ int   lcnt;
  __shared__ int   hsl[TILE], tsl[TILE];
  __shared__ float part[8][TILE];
  __shared__ float ets[TILE][RANK];

  if (threadIdx.x == 0) lcnt = 0;
  __syncthreads();

  // W_r slice first: latency overlaps the scan below.
  float2 wreg[16];
  const float2* W2 = (const float2*)(W + (size_t)r * RANK * RANK);
  #pragma unroll
  for (int d = 0; d < 16; ++d)
    wreg[d] = W2[(wib * 16 + d) * 64 + lane];

  // ---- scan rels, compact matching indices ----
  const int nb4 = batch >> 2;
  const int4* r4 = (const int4*)rels;
  for (int i = threadIdx.x; i < nb4; i += 512) {
    const int4 v = r4[i];
    if (v.x == r) { int p = atomicAdd(&lcnt, 1); if (p < LCAP) list[p] = 4*i;   }
    if (v.y == r) { int p = atomicAdd(&lcnt, 1); if (p < LCAP) list[p] = 4*i+1; }
    if (v.z == r) { int p = atomicAdd(&lcnt, 1); if (p < LCAP) list[p] = 4*i+2; }
    if (v.w == r) { int p = atomicAdd(&lcnt, 1); if (p < LCAP) list[p] = 4*i+3; }
  }
  for (int i = 4*nb4 + threadIdx.x; i < batch; i += 512)
    if (rels[i] == r) { int p = atomicAdd(&lcnt, 1); if (p < LCAP) list[p] = i; }

  __syncthreads();
  const int cnt = min(lcnt, LCAP);

  for (int tb = 0; tb < cnt; tb += TILE) {
    const int tc  = min(TILE, cnt - tb);
    const int tcp = (tc + 3) & ~3;       // padded count (clamped dup elems)
    const int ng  = tcp >> 2;            // 4-elem groups, block-uniform

    int bv = 0;
    if (threadIdx.x < TILE) {            // wave-0 lanes publish clamped indices
      bv = list[tb + min(l31, tc - 1)];
      hsl[l31] = heads[bv];
      tsl[l31] = tails[bv];
    }
    __syncthreads();

    // ---- ALL tile memory up-front, one latency exposure ----
    float ehg[8];
    #pragma unroll
    for (int g = 0; g < 8; ++g) {
      if (g < ng) {                      // block-uniform branch
        const int hh = hsl[4 * g + (lane >> 4)];
        ehg[g] = E[(size_t)(unsigned)hh * RANK + wib * 16 + (lane & 15)];
      }
    }
    const int nf4 = tcp * 32;            // stage padded rows too (dups, valid)
    for (int idx = threadIdx.x; idx < nf4; idx += 512) {
      const int e = idx >> 5, w4 = idx & 31;
      ((float4*)ets[e])[w4] =
          ((const float4*)(E + (size_t)(unsigned)tsl[e] * RANK))[w4];
    }
    __syncthreads();

    // ---- pure-VALU compute, clamp-free ----
    for (int g = 0; g < ng; ++g) {
      #pragma unroll
      for (int u = 0; u < 4; ++u) {
        const int e = 4 * g + u;
        const float2 et = ((const float2*)ets[e])[lane];

        float mx = 0.f, my = 0.f;
        #pragma unroll
        for (int d = 0; d < 16; ++d) {
          const float x = __int_as_float(__builtin_amdgcn_readlane(
              __float_as_int(ehg[g]), u * 16 + d));
          mx = fmaf(x, wreg[d].x, mx);
          my = fmaf(x, wreg[d].y, my);
        }

        float sv = fmaf(mx, et.x, my * et.y);
        sv = dpp_sum64(sv);
        if (lane == 63 && e < tc) part[wib][e] = sv;
      }
    }
    __syncthreads();

    if (threadIdx.x < tc) {              // wave-0 lane l holds bv for elem l
      float tot = 0.f;
      #pragma unroll
      for (int w = 0; w < 8; ++w) tot += part[w][threadIdx.x];
      out[bv] = tot;
    }
    if (tb + TILE < cnt) __syncthreads();   // only if another tile follows
  }
}

extern "C" void kernel_launch(void* const* d_in, const int* in_sizes, int n_in,
                              void* d_out, int out_size, void* d_ws, size_t ws_size,
                              hipStream_t stream)
{
  const float* E     = (const float*)d_in[0];
  const float* W     = (const float*)d_in[1];
  const int*   heads = (const int*)d_in[2];
  const int*   rels  = (const int*)d_in[3];
  const int*   tails = (const int*)d_in[4];
  float* out = (float*)d_out;

  const int batch = in_sizes[2];                  // 16384
  const int nrel  = in_sizes[1] / (RANK * RANK);  // 1000

  rescal_one<<<nrel, 512, 0, stream>>>(E, W, heads, rels, tails, out, batch);
}